// Round 10
// baseline (176.363 us; speedup 1.0000x reference)
//
#include <hip/hip_runtime.h>

// InputPreprocessor — B=2048, N=32, M=8, D_PAIR=37, H=128.
// features_el_el in the reference is DEAD CODE. Live outputs (both f32):
//   out0 = features_el  [B,N,424]  (ion-summed 2-layer silu MLP || flat feats)
//   out1 = features_ion [B,8,32]
// R16 = R15 (74.0 µs el) + spill-safe issue-count cuts. Occupancy is CLOSED
// twice over: (a) R11/R13/R14 spilled at every cap < 128 regs (unified
// VGPR+AGPR demand ~100+); (b) at 128 regs the 512-reg file itself caps
// 4 waves/SIMD, so LDS-freeing can't help either. Levers = op counts only:
//  - b1 folded into l1 accumulator INIT (MFMA adds bias for free): -32 VALU.
//  - exp2-domain RBF: is2 = is*sqrt(log2e) hoisted, dL = d*log2e once, then
//    val = d2 * v_exp_f32(fma(-uu,uu,-dL)) (raw 2^x, no per-exp ln2 mul): -8.
//  - tail stores: only phase 3 writes orow[36]/featb-dz (was 4x idempotent).
//  - last iteration skips the idempotent feat(0) recompute (uniform branch).
// Carried from R12/R15: cross-iter feat pipeline (featA/featB disjoint double
// buffer, branchless feat core), contiguous RBF ownership (phase owns
// k=8p..8p+7 -> one ds_write_b128), pair-rcp silu2, rolling h0c l0->l1
// handoff (stride-40, bank-uniform), W0L/W1L in LDS, v_cvt_pk_bf16_f32,
// bias0 via 1.0-feature, b1/mu/sigma hoisted, 2-deep r prefetch, ion folded
// in, setprio around l1, LDS 79872 B = 2 blocks/CU, __launch_bounds__(512,4).

typedef __attribute__((ext_vector_type(8))) short short8;
typedef __attribute__((ext_vector_type(4))) float f32x4;
typedef __attribute__((ext_vector_type(4))) int   int4v;

#define ITERS     8
#define UNITS_IT  16          // units per block-iteration (128 edges)
#define ROWLEN    424
#define OUT_EL    27787264    // 65536*424

__device__ __forceinline__ unsigned short f2bf(float f){   // prologue staging only
    unsigned int u = __builtin_bit_cast(unsigned int, f);
    u += 0x7fffu + ((u >> 16) & 1u);     // RNE
    return (unsigned short)(u >> 16);
}
__device__ __forceinline__ unsigned int cvtpk_bf16(float lo, float hi){
    unsigned int r;
    asm("v_cvt_pk_bf16_f32 %0, %1, %2" : "=v"(r) : "v"(lo), "v"(hi));
    return r;   // [15:0]=bf16(lo), [31:16]=bf16(hi), RNE
}
__device__ __forceinline__ unsigned short bf16s(float x){
    return (unsigned short)cvtpk_bf16(x, x);
}
__device__ __forceinline__ float exp2_raw(float x){        // 2^x, no ln2 mul
    float r;
    asm("v_exp_f32 %0, %1" : "=v"(r) : "v"(x));
    return r;
}
__device__ __forceinline__ float fast_silu(float x){
    return x * __builtin_amdgcn_rcpf(1.0f + __expf(-x));
}
// two silus, one rcp (shared denominator). Overflow needs x0+x1 < -177
// with each > -88.7 — unreachable for these activations (|acc| <~ 30).
__device__ __forceinline__ void silu2(float x0, float x1, float& s0, float& s1){
    float pA = 1.0f + __expf(-x0);
    float pB = 1.0f + __expf(-x1);
    float rp = __builtin_amdgcn_rcpf(pA * pB);
    s0 = x0 * pB * rp;
    s1 = x1 * pA * rp;
}

__global__ __launch_bounds__(512, 4)
void el_kernel(const float* __restrict__ r,
               const float* __restrict__ Rion,
               const float* __restrict__ W0,
               const float* __restrict__ b0,
               const float* __restrict__ W1,
               const float* __restrict__ b1,
               const float* __restrict__ Z,
               const float* __restrict__ Wion,
               const float* __restrict__ bion,
               float* __restrict__ out)
{
    // MFMA-read layouts are [tile][chunk][lane64][8 shorts]: b128 = base+lane*16.
    __shared__ __align__(16) unsigned short W0L[8][2][64][8];   // 16384 B
    __shared__ __align__(16) unsigned short W1L[8][4][64][8];   // 32768 B
    // Per-wave 3840B, three DISJOINT regions (no aliasing, no barriers):
    //   shorts [0,640)     : featA (k<32: [4][16][8]; tails+1.0+pad: [16][8])
    //   shorts [640,1280)  : featB (same layout; double buffer)
    //   shorts [1280,1920) : h0c rolling [16 edges][40] (l0->l1 chunk handoff)
    __shared__ __align__(16) unsigned short UNI[8][1920];       // 30720 B
    // total 79872 B -> 2 blocks (1024 thr) / CU = 16 waves/CU

    const int t    = threadIdx.x;
    const int lane = t & 63;
    const int w    = t >> 6;       // wave 0..7, owns units 2w,2w+1 (16 edges)
    const int quad = lane >> 4;
    const int l16  = lane & 15;

    // ---- stage W0L: A-frag for layer 0 (M=channel, K=feature) ----
    for (int i = t; i < 8*2*64*8; i += 512){
        int j = i & 7, ln = (i >> 3) & 63, ch = (i >> 9) & 1, tc = i >> 10;
        int q = ln >> 4, n = tc*16 + (ln & 15);
        float v = 0.f;
        if (ch == 0)            v = W0[(q*8 + j)*128 + n];
        else if (q == 0){
            if      (j < 5)     v = W0[(32 + j)*128 + n];
            else if (j == 5)    v = b0[n];                 // bias via 1.0-feature
        }
        ((unsigned short*)W0L)[i] = f2bf(v);
    }
    // ---- stage W1L: B-frag for layer 1 (K=channel, N=out-channel) ----
    for (int i = t; i < 8*4*64*8; i += 512){
        int j = i & 7, ln = (i >> 3) & 63, c = (i >> 9) & 3, tc = i >> 11;
        int k = c*32 + (ln >> 4)*8 + j, n = tc*16 + (ln & 15);
        ((unsigned short*)W1L)[i] = f2bf(W1[k*128 + n]);
    }
    // ---- constant tail slots, BOTH feat buffers, once:
    // slot 5 = 1.0 (bias feature), slots 6,7 = 0.0 (k=38,39 pad).
    // Without init, it=0 reads raw LDS garbage; bf16 Inf/NaN x 0.0 weight
    // row = NaN inside the layer-0 MFMA (R8 lesson).
    if (t < 128){
        int ww = t >> 4, e = t & 15;
        #pragma unroll
        for (int b = 0; b < 2; ++b){
            UNI[ww][b*640 + 512 + e*8 + 5] = 0x3F80;
            UNI[ww][b*640 + 512 + e*8 + 6] = 0;
            UNI[ww][b*640 + 512 + e*8 + 7] = 0;
        }
    }

    // ---- ion output folded in: 2 elements per thread (524288 total) ----
    {
        int e0 = (blockIdx.x*512 + t)*2;           // even -> j0 < 31, no wrap
        int j0 = e0 & 31, mm = (e0 >> 5) & 7;
        float z = Z[mm];
        float2 v;
        v.x = fast_silu(z * Wion[j0]     + bion[j0]);
        v.y = fast_silu(z * Wion[j0 + 1] + bion[j0 + 1]);
        *(float2*)&out[OUT_EL + e0] = v;
    }

    // feature-phase mapping: 4 threads per edge; wave-local (frow>>4 == w)
    const int frow  = t >> 2;      // edge 0..127 = ul*8 + m
    const int phase = t & 3;
    const int ul    = frow >> 3;   // block-local unit 0..15
    const int m     = frow & 7;
    const int e16   = frow & 15;   // wave-local edge
    const float Rx = Rion[m*3+0];
    const float Ry = Rion[m*3+1];
    const float Rz = Rion[m*3+2];

    unsigned short* const uw = &UNI[w][0];

    const f32x4 zeroc = {0.f,0.f,0.f,0.f};

    // hoist layer-1 bias (8 VGPRs); used as the l1 accumulator INIT
    float bias1[8];
    #pragma unroll
    for (int tc = 0; tc < 8; ++tc) bias1[tc] = b1[tc*16 + l16];

    // hoist per-thread RBF constants in exp2 domain: k = 8*phase + kk.
    // val = d2 * exp(-d - ((d-mu)*is)^2) = d2 * 2^(-d*L - ((d-mu)*is*sqrtL)^2)
    const float L  = 1.44269504088896341f;   // log2(e)
    const float sL = 1.20112240878645986f;   // sqrt(log2(e))
    float muA[8], is2A[8];
    #pragma unroll
    for (int kk = 0; kk < 8; ++kk){
        float q = (float)(phase*8 + kk) * (1.0f/31.0f);
        muA[kk]  = q*q*5.0f;
        is2A[kk] = 7.0f * sL * __builtin_amdgcn_rcpf(1.0f + 5.0f*q);
    }

    const int ubase0 = blockIdx.x * (UNITS_IT * ITERS);

    // Branchless feature core: computes edge (gu, m)'s 37 features, stores
    // exact f32 to out and bf16 to feat buffer at short-offset fb.
    // This lane owns RBF k = 8*phase..8*phase+7 -> one ds_write_b128.
    auto feat_pass = [&](int gu, int fb, float px, float py, float pz){
        float dx = px - Rx, dy = py - Ry, dz = pz - Rz;
        float d2 = dx*dx + dy*dy + dz*dz;
        float d  = __builtin_amdgcn_sqrtf(d2);
        float dL = d * L;                         // exp2-domain linear term
        float* orow = &out[(size_t)gu*ROWLEN + 128 + m*37];
        int4v pkv;
        #pragma unroll
        for (int jp = 0; jp < 4; ++jp){
            float uu0 = (d - muA[2*jp])   * is2A[2*jp];
            float v0  = d2 * exp2_raw(__builtin_fmaf(-uu0, uu0, -dL));
            float uu1 = (d - muA[2*jp+1]) * is2A[2*jp+1];
            float v1  = d2 * exp2_raw(__builtin_fmaf(-uu1, uu1, -dL));
            orow[phase*8 + 2*jp]     = v0;
            orow[phase*8 + 2*jp + 1] = v1;
            pkv[jp] = (int)cvtpk_bf16(v0, v1);
        }
        *(int4v*)&uw[fb + phase*128 + e16*8] = pkv;   // chunk[phase], 16B aligned
        // tails: this phase's slot; phase 3 additionally owns dz (slot 36/4)
        float tv = (phase == 0) ? d :
                   (phase == 1) ? __builtin_amdgcn_rcpf(d + 0.01f) :
                   (phase == 2) ? dx : dy;
        orow[32 + phase] = tv;
        uw[fb + 512 + e16*8 + phase] = bf16s(tv);
        if (phase == 3){
            orow[36] = dz;
            uw[fb + 512 + e16*8 + 4] = bf16s(dz);
        }
    };

    // ---- prologue: feat(0) into featA; prefetch r(1) ----
    {
        int gu = ubase0 + ul;
        feat_pass(gu, 0, r[gu*3+0], r[gu*3+1], r[gu*3+2]);
    }
    float cx, cy, cz;
    {
        int gu = ubase0 + UNITS_IT + ul;     // r(1) (ITERS>=2)
        cx = r[gu*3+0]; cy = r[gu*3+1]; cz = r[gu*3+2];
    }

    __syncthreads();   // weights staged; loop body is wave-local, barrier-free

    int cur = 0;       // short-offset of current feat buffer (0 or 640)
    for (int it = 0; it < ITERS; ++it){
        const int ubase = ubase0 + it * UNITS_IT;

        // prefetch r((it+2) & 7) — wrapped, branchless
        int gun = ubase0 + (((it + 2) & (ITERS-1)) * UNITS_IT) + ul;
        float nx = r[gun*3+0], ny = r[gun*3+1], nz = r[gun*3+2];

        // current iteration's B-frags (featA/B[cur]; written a full iter ago)
        short8 bf0 = *(const short8*)&uw[cur + quad*128 + l16*8];   // k = quad*8+j
        short8 bf1 = *(const short8*)&uw[cur + 512 + l16*8];        // k = 32+j

        // feat for it+1 into the OTHER buffer (wave-uniform skip on last iter;
        // feat(0) already computed in the prologue)
        if (it != ITERS-1){
            int gu = ubase0 + (it + 1) * UNITS_IT + ul;
            feat_pass(gu, cur ^ 640, cx, cy, cz);
        }

        // ---------- fused layer0/layer1, rolling h0 chunk ----------
        // l1 bias folded into accumulator init (MFMA adds it for free)
        f32x4 acc1[8];
        #pragma unroll
        for (int i = 0; i < 8; ++i){
            f32x4 binit = {bias1[i], bias1[i], bias1[i], bias1[i]};
            acc1[i] = binit;
        }

        #pragma unroll
        for (int c = 0; c < 4; ++c){
            // l0 steps tc=2c, 2c+1 produce exactly k-chunk c = [32c, 32c+32)
            #pragma unroll
            for (int h = 0; h < 2; ++h){
                const int tc = 2*c + h;
                short8 a0 = *(const short8*)&W0L[tc][0][lane][0];
                short8 a1 = *(const short8*)&W0L[tc][1][lane][0];
                f32x4 acc = __builtin_amdgcn_mfma_f32_16x16x32_bf16(a0, bf0, zeroc, 0, 0, 0);
                acc       = __builtin_amdgcn_mfma_f32_16x16x32_bf16(a1, bf1, acc,   0, 0, 0);
                // C-layout: lane holds ch n = tc*16 + quad*4 + rr, edge = l16.
                float s0, s1, s2, s3;
                silu2(acc[0], acc[1], s0, s1);
                silu2(acc[2], acc[3], s2, s3);
                unsigned int p01 = cvtpk_bf16(s0, s1);
                unsigned int p23 = cvtpk_bf16(s2, s3);
                unsigned long long pk = (unsigned long long)p01 |
                                        ((unsigned long long)p23 << 32);
                // h0c[edge=l16][ch32 = h*16+quad*4 ..+3]; stride-40 rows:
                // b64 write = 4 accesses/bank uniform (conflict-free)
                *(unsigned long long*)&uw[1280 + l16*40 + h*16 + quad*4] = pk;
            }
            // A-frag chunk c: h0c[edge=l16][ch32 = quad*8 + j]
            // b128 read = 8 accesses/bank uniform (conflict-free)
            short8 afk = *(const short8*)&uw[1280 + l16*40 + quad*8];
            __builtin_amdgcn_s_setprio(1);   // pure-MFMA run; waves phase-diverse
            #pragma unroll
            for (int tc2 = 0; tc2 < 8; ++tc2){
                short8 bw = *(const short8*)&W1L[tc2][c][lane][0];
                acc1[tc2] = __builtin_amdgcn_mfma_f32_16x16x32_bf16(afk, bw, acc1[tc2], 0, 0, 0);
            }
            __builtin_amdgcn_s_setprio(0);
        }

        // silu + ion-sum over rows (rr spans edges), store one_el f32
        #pragma unroll
        for (int tc = 0; tc < 8; ++tc){
            float s0, s1, s2, s3;
            silu2(acc1[tc][0], acc1[tc][1], s0, s1);
            silu2(acc1[tc][2], acc1[tc][3], s2, s3);
            float v = (s0 + s1) + (s2 + s3);
            v += __shfl_xor(v, 16, 64);   // quad0+1 -> unit 2w; quad2+3 -> unit 2w+1
            if ((quad & 1) == 0){
                size_t gu = (size_t)(ubase + 2*w + (quad >> 1));
                out[gu*ROWLEN + tc*16 + l16] = v;
            }
        }

        cur ^= 640;                    // swap feat buffers
        cx = nx; cy = ny; cz = nz;     // rotate r pipeline
    }
}

extern "C" void kernel_launch(void* const* d_in, const int* in_sizes, int n_in,
                              void* d_out, int out_size, void* d_ws, size_t ws_size,
                              hipStream_t stream)
{
    const float* r    = (const float*)d_in[0];
    const float* Rion = (const float*)d_in[1];
    const float* Z    = (const float*)d_in[2];
    const float* W0   = (const float*)d_in[3];
    const float* b0   = (const float*)d_in[4];
    const float* W1   = (const float*)d_in[5];
    const float* b1   = (const float*)d_in[6];
    const float* Wion = (const float*)d_in[7];
    const float* bion = (const float*)d_in[8];
    float* out = (float*)d_out;

    el_kernel<<<dim3(512), dim3(512), 0, stream>>>(r, Rion, W0, b0, W1, b1,
                                                   Z, Wion, bion, out);
}